// Round 2
// baseline (554.646 us; speedup 1.0000x reference)
//
#include <hip/hip_runtime.h>
#include <hip/hip_bf16.h>
#include <stdint.h>

#define CATS  32
#define DI    1024
#define DO    1024
#define NB    64
#define ST    512

typedef float  f32x4  __attribute__((ext_vector_type(4)));
typedef short  bf16x8 __attribute__((ext_vector_type(8)));

__device__ __forceinline__ unsigned short f2bf(float f) {
    union { float f; unsigned int u; } v;
    v.f = f;
    unsigned int r = v.u + 0x7FFFu + ((v.u >> 16) & 1u);  // RNE
    return (unsigned short)(r >> 16);
}

// ---------------- Pass 1a: W (C,I,O) fp32 -> Wt (C,O,I) bf16 ----------------
__global__ __launch_bounds__(256) void wt_transpose_kernel(
        const float* __restrict__ W, unsigned short* __restrict__ Wt) {
    __shared__ float tile[64 * 65];
    const int c  = blockIdx.z;
    const int i0 = blockIdx.y * 64;
    const int o0 = blockIdx.x * 64;
    const float* Wc = W + (size_t)c * DI * DO;
    const int tid = threadIdx.x;

    const int f  = tid & 15;
    const int r0 = tid >> 4;
    #pragma unroll
    for (int rr = 0; rr < 4; ++rr) {
        const int r = r0 + rr * 16;
        const f32x4 v = *(const f32x4*)(Wc + (size_t)(i0 + r) * DO + (o0 + 4 * f));
        #pragma unroll
        for (int j = 0; j < 4; ++j)
            tile[r * 65 + 4 * f + j] = v[j];
    }
    __syncthreads();

    const int g   = tid & 7;
    const int ol0 = tid >> 3;
    unsigned short* WtC = Wt + (size_t)c * DO * DI;
    #pragma unroll
    for (int oo = 0; oo < 2; ++oo) {
        const int ol = ol0 + oo * 32;
        unsigned int w[4];
        #pragma unroll
        for (int j = 0; j < 4; ++j) {
            const unsigned short lo = f2bf(tile[(8 * g + 2 * j + 0) * 65 + ol]);
            const unsigned short hi = f2bf(tile[(8 * g + 2 * j + 1) * 65 + ol]);
            w[j] = (unsigned int)lo | ((unsigned int)hi << 16);
        }
        uint4 pk; pk.x = w[0]; pk.y = w[1]; pk.z = w[2]; pk.w = w[3];
        *(uint4*)(WtC + (size_t)(o0 + ol) * DI + (i0 + 8 * g)) = pk;
    }
}

// ---------------- Pass 1b: x fp32 -> xb bf16 (same [B,T,I] layout) ----------------
__global__ __launch_bounds__(256) void x_convert_kernel(
        const float* __restrict__ x, unsigned short* __restrict__ xb) {
    const size_t i = ((size_t)blockIdx.x * 256 + threadIdx.x) * 8;
    const f32x4 v0 = *(const f32x4*)(x + i);
    const f32x4 v1 = *(const f32x4*)(x + i + 4);
    uint4 pk;
    pk.x = (unsigned int)f2bf(v0[0]) | ((unsigned int)f2bf(v0[1]) << 16);
    pk.y = (unsigned int)f2bf(v0[2]) | ((unsigned int)f2bf(v0[3]) << 16);
    pk.z = (unsigned int)f2bf(v1[0]) | ((unsigned int)f2bf(v1[1]) << 16);
    pk.w = (unsigned int)f2bf(v1[2]) | ((unsigned int)f2bf(v1[3]) << 16);
    *(uint4*)(xb + i) = pk;
}

// ---------------- Pass 2: LDS-free per-category GEMM ----------------
// Block 256 thr = 4 waves, tile M=64 x N=256, each wave 64x64.
// A and B fragments loaded direct global->register (both k-contiguous bf16).
// XB=1: A from pre-converted xb (bf16). XB=0: A from fp32 x, cvt in-register.
template<int XB>
__global__ __launch_bounds__(256) void cat_gemm_kernel(
        const unsigned short* __restrict__ xb, const float* __restrict__ xf,
        const int* __restrict__ cat_ids,
        const unsigned short* __restrict__ Wt, const float* __restrict__ bias,
        float* __restrict__ out) {
    const int b    = blockIdx.z;
    const int mblk = blockIdx.y;            // 8 tiles of 64 along T
    const int nblk = blockIdx.x;            // 4 tiles of 256 along O
    const int cat  = cat_ids[b];

    const int tid  = threadIdx.x;
    const int lane = tid & 63;
    const int wv   = tid >> 6;              // wave -> n sub-tile
    const int l15  = lane & 15;
    const int kg   = lane >> 4;             // k-quad

    const int mrow = mblk * 64 + l15;       // + mi*16
    const int ncol = nblk * 256 + wv * 64 + l15;  // + ni*16

    const unsigned short* ap_h =
        XB ? xb + (size_t)(b * ST + mrow) * DI + kg * 8 : nullptr;
    const float* ap_f =
        XB ? nullptr : xf + (size_t)(b * ST + mrow) * DI + kg * 8;
    const unsigned short* bp =
        Wt + ((size_t)cat * DO + ncol) * DI + kg * 8;

    f32x4 acc[4][4];
    #pragma unroll
    for (int mi = 0; mi < 4; ++mi)
        #pragma unroll
        for (int ni = 0; ni < 4; ++ni)
            acc[mi][ni] = (f32x4){0.f, 0.f, 0.f, 0.f};

    #define LOAD_A(dst, k0)                                                    \
        do {                                                                   \
            if (XB) {                                                          \
                _Pragma("unroll")                                              \
                for (int mi = 0; mi < 4; ++mi)                                 \
                    dst[mi] = *(const bf16x8*)(ap_h + (size_t)mi * 16 * DI + (k0)); \
            } else {                                                           \
                _Pragma("unroll")                                              \
                for (int mi = 0; mi < 4; ++mi) {                               \
                    const f32x4 u0 = *(const f32x4*)(ap_f + (size_t)mi * 16 * DI + (k0));     \
                    const f32x4 u1 = *(const f32x4*)(ap_f + (size_t)mi * 16 * DI + (k0) + 4); \
                    bf16x8 r;                                                  \
                    r[0] = (short)f2bf(u0[0]); r[1] = (short)f2bf(u0[1]);      \
                    r[2] = (short)f2bf(u0[2]); r[3] = (short)f2bf(u0[3]);      \
                    r[4] = (short)f2bf(u1[0]); r[5] = (short)f2bf(u1[1]);      \
                    r[6] = (short)f2bf(u1[2]); r[7] = (short)f2bf(u1[3]);      \
                    dst[mi] = r;                                               \
                }                                                              \
            }                                                                  \
        } while (0)

    #define LOAD_B(dst, k0)                                                    \
        do {                                                                   \
            _Pragma("unroll")                                                  \
            for (int ni = 0; ni < 4; ++ni)                                     \
                dst[ni] = *(const bf16x8*)(bp + (size_t)ni * 16 * DI + (k0));  \
        } while (0)

    bf16x8 a0[4], b0[4], a1[4], b1[4];
    LOAD_A(a0, 0);
    LOAD_B(b0, 0);

    #pragma unroll
    for (int k0 = 0; k0 < DI; k0 += 64) {
        LOAD_A(a1, k0 + 32);
        LOAD_B(b1, k0 + 32);
        #pragma unroll
        for (int mi = 0; mi < 4; ++mi)
            #pragma unroll
            for (int ni = 0; ni < 4; ++ni)
                acc[mi][ni] = __builtin_amdgcn_mfma_f32_16x16x32_bf16(
                                  a0[mi], b0[ni], acc[mi][ni], 0, 0, 0);
        if (k0 + 64 < DI) {
            LOAD_A(a0, k0 + 64);
            LOAD_B(b0, k0 + 64);
        }
        #pragma unroll
        for (int mi = 0; mi < 4; ++mi)
            #pragma unroll
            for (int ni = 0; ni < 4; ++ni)
                acc[mi][ni] = __builtin_amdgcn_mfma_f32_16x16x32_bf16(
                                  a1[mi], b1[ni], acc[mi][ni], 0, 0, 0);
    }
    #undef LOAD_A
    #undef LOAD_B

    // epilogue: C/D layout col = lane&15, row = (lane>>4)*4 + r
    float bs[4];
    #pragma unroll
    for (int ni = 0; ni < 4; ++ni)
        bs[ni] = bias[(size_t)cat * DO + ncol + ni * 16];

    #pragma unroll
    for (int mi = 0; mi < 4; ++mi) {
        const int rowb = mblk * 64 + mi * 16 + kg * 4;
        #pragma unroll
        for (int r = 0; r < 4; ++r) {
            float* orow = out + (size_t)(b * ST + rowb + r) * DO + ncol;
            #pragma unroll
            for (int ni = 0; ni < 4; ++ni)
                orow[ni * 16] = acc[mi][ni][r] + bs[ni];
        }
    }
}

// ---------------- Fallback: correct fp32 path ----------------
__global__ __launch_bounds__(256) void naive_kernel(
        const float* __restrict__ x, const int* __restrict__ cat_ids,
        const float* __restrict__ W, const float* __restrict__ bias,
        float* __restrict__ out) {
    const int bt = blockIdx.x;
    const int b  = bt >> 9;
    const int t  = bt & 511;
    const int cat = cat_ids[b];
    const float* xr = x + ((size_t)b * ST + t) * DI;
    const float* Wc = W + (size_t)cat * DI * DO;
    const int o = threadIdx.x;
    float a0 = bias[cat * DO + o];
    float a1 = bias[cat * DO + o + 256];
    float a2 = bias[cat * DO + o + 512];
    float a3 = bias[cat * DO + o + 768];
    for (int i = 0; i < DI; ++i) {
        const float xv = xr[i];
        const float* wrow = Wc + (size_t)i * DO;
        a0 += xv * wrow[o];
        a1 += xv * wrow[o + 256];
        a2 += xv * wrow[o + 512];
        a3 += xv * wrow[o + 768];
    }
    float* orow = out + ((size_t)b * ST + t) * DO;
    orow[o] = a0; orow[o + 256] = a1; orow[o + 512] = a2; orow[o + 768] = a3;
}

extern "C" void kernel_launch(void* const* d_in, const int* in_sizes, int n_in,
                              void* d_out, int out_size, void* d_ws, size_t ws_size,
                              hipStream_t stream) {
    const float* x    = (const float*)d_in[0];
    const int*   cats = (const int*)d_in[1];
    const float* W    = (const float*)d_in[2];
    const float* bias = (const float*)d_in[3];
    float*       out  = (float*)d_out;

    const size_t wt_bytes = (size_t)CATS * DI * DO * sizeof(unsigned short); // 64 MiB
    const size_t xb_bytes = (size_t)NB * ST * DI * sizeof(unsigned short);   // 64 MiB

    if (ws_size >= wt_bytes + xb_bytes) {
        unsigned short* Wt = (unsigned short*)d_ws;
        unsigned short* xb = (unsigned short*)((char*)d_ws + wt_bytes);
        wt_transpose_kernel<<<dim3(DO / 64, DI / 64, CATS), 256, 0, stream>>>(W, Wt);
        x_convert_kernel<<<(NB * ST * DI) / (256 * 8), 256, 0, stream>>>(x, xb);
        cat_gemm_kernel<1><<<dim3(DO / 256, ST / 64, NB), 256, 0, stream>>>(
            xb, nullptr, cats, Wt, bias, out);
    } else if (ws_size >= wt_bytes) {
        unsigned short* Wt = (unsigned short*)d_ws;
        wt_transpose_kernel<<<dim3(DO / 64, DI / 64, CATS), 256, 0, stream>>>(W, Wt);
        cat_gemm_kernel<0><<<dim3(DO / 256, ST / 64, NB), 256, 0, stream>>>(
            nullptr, x, cats, Wt, bias, out);
    } else {
        naive_kernel<<<NB * ST, 256, 0, stream>>>(x, cats, W, bias, out);
    }
}

// Round 3
// 429.789 us; speedup vs baseline: 1.2905x; 1.2905x over previous
//
#include <hip/hip_runtime.h>
#include <hip/hip_bf16.h>
#include <stdint.h>

#define CATS  32
#define DI    1024
#define DO    1024
#define NB    64
#define ST    512

typedef float  f32x4  __attribute__((ext_vector_type(4)));
typedef short  bf16x8 __attribute__((ext_vector_type(8)));

__device__ __forceinline__ unsigned short f2bf(float f) {
    union { float f; unsigned int u; } v;
    v.f = f;
    unsigned int r = v.u + 0x7FFFu + ((v.u >> 16) & 1u);  // RNE
    return (unsigned short)(r >> 16);
}

// ---------------- Pass 1a: W (C,I,O) fp32 -> Wt (C,O,I) bf16 ----------------
// Tile 128(i) x 64(o). Reads 128 x 256B contiguous; writes 64 rows x 256B
// contiguous (16 lanes x 16B). LDS fp32 tile stride 65 (phase-2 reads 4-way,
// acceptable; phase-1 writes 2-way = free).
__global__ __launch_bounds__(256) void wt_transpose_kernel(
        const float* __restrict__ W, unsigned short* __restrict__ Wt) {
    __shared__ float tile[128 * 65];
    const int c  = blockIdx.z;
    const int i0 = blockIdx.y * 128;
    const int o0 = blockIdx.x * 64;
    const float* Wc = W + (size_t)c * DI * DO;
    const int tid = threadIdx.x;

    const int f  = tid & 15;    // o chunk of 4
    const int r0 = tid >> 4;    // 0..15
    #pragma unroll
    for (int rr = 0; rr < 8; ++rr) {
        const int r = r0 + rr * 16;
        const f32x4 v = *(const f32x4*)(Wc + (size_t)(i0 + r) * DO + (o0 + 4 * f));
        #pragma unroll
        for (int j = 0; j < 4; ++j)
            tile[r * 65 + 4 * f + j] = v[j];
    }
    __syncthreads();

    const int g   = tid & 15;   // i chunk of 8 (16 chunks cover 128 i)
    const int ol0 = tid >> 4;   // 0..15
    unsigned short* WtC = Wt + (size_t)c * DO * DI;
    #pragma unroll
    for (int oo = 0; oo < 4; ++oo) {
        const int ol = ol0 + oo * 16;
        unsigned int w[4];
        #pragma unroll
        for (int j = 0; j < 4; ++j) {
            const unsigned short lo = f2bf(tile[(8 * g + 2 * j + 0) * 65 + ol]);
            const unsigned short hi = f2bf(tile[(8 * g + 2 * j + 1) * 65 + ol]);
            w[j] = (unsigned int)lo | ((unsigned int)hi << 16);
        }
        uint4 pk; pk.x = w[0]; pk.y = w[1]; pk.z = w[2]; pk.w = w[3];
        *(uint4*)(WtC + (size_t)(o0 + ol) * DI + (i0 + 8 * g)) = pk;
    }
}

// ---------------- Pass 1b: x fp32 -> xb bf16 ----------------
__global__ __launch_bounds__(256) void x_convert_kernel(
        const float* __restrict__ x, unsigned short* __restrict__ xb) {
    const size_t i = ((size_t)blockIdx.x * 256 + threadIdx.x) * 8;
    const f32x4 v0 = *(const f32x4*)(x + i);
    const f32x4 v1 = *(const f32x4*)(x + i + 4);
    uint4 pk;
    pk.x = (unsigned int)f2bf(v0[0]) | ((unsigned int)f2bf(v0[1]) << 16);
    pk.y = (unsigned int)f2bf(v0[2]) | ((unsigned int)f2bf(v0[3]) << 16);
    pk.z = (unsigned int)f2bf(v1[0]) | ((unsigned int)f2bf(v1[1]) << 16);
    pk.w = (unsigned int)f2bf(v1[2]) | ((unsigned int)f2bf(v1[3]) << 16);
    *(uint4*)(xb + i) = pk;
}

// ---------------- Pass 2: m97-style LDS-staged GEMM ----------------
// Block 256 thr = 4 waves (2x2), tile M=128 x N=128, BK=32, double-buffered.
// Both A (xb) and B (Wt) staged via global_load_lds width=16.
// LDS rows are 32 bf16 = 64 B, no padding (gll requires lane-ordered dest);
// k-chunks XOR-swizzled by ((row>>1)&3) so ds_read_b128 frags are 2-way max.
#define BM 128
#define BN 128
#define BK 32

__global__ __launch_bounds__(256) void cat_gemm_kernel(
        const unsigned short* __restrict__ xb, const int* __restrict__ cat_ids,
        const unsigned short* __restrict__ Wt, const float* __restrict__ bias,
        float* __restrict__ out) {
    __shared__ __align__(16) unsigned short As[2][BM * BK];  // 2 x 8 KB
    __shared__ __align__(16) unsigned short Bs[2][BN * BK];  // 2 x 8 KB

    const int b     = blockIdx.z;
    const int mbase = blockIdx.y * BM;
    const int nbase = blockIdx.x * BN;
    const int cat   = cat_ids[b];

    const int tid  = threadIdx.x;
    const int lane = tid & 63;
    const int w    = tid >> 6;
    const int wr   = w >> 1;       // m half
    const int wc   = w & 1;        // n half
    const int l15  = lane & 15;
    const int kg   = lane >> 4;

    // staging: wave w covers rows [w*32, w*32+32), 2 gll per operand
    const int sr     = lane >> 2;                       // row within 16-chunk
    const int schunk = (lane & 3) ^ ((lane >> 3) & 3);  // XOR-swizzled 16B chunk

    const unsigned short* gA = xb + (size_t)(b * ST + mbase) * DI;
    const unsigned short* gB = Wt + ((size_t)cat * DO + nbase) * DI;

    // fragment read offsets (swizzle (m>>1)&3 == (l15>>1)&3 since tiles are x16)
    const int koff = (kg ^ ((l15 >> 1) & 3)) * 8;  // ushort units

    f32x4 acc[4][4];
    #pragma unroll
    for (int mi = 0; mi < 4; ++mi)
        #pragma unroll
        for (int ni = 0; ni < 4; ++ni)
            acc[mi][ni] = (f32x4){0.f, 0.f, 0.f, 0.f};

    #define STAGE(bufi, k0)                                                          \
        do {                                                                         \
            _Pragma("unroll")                                                        \
            for (int q = 0; q < 2; ++q) {                                            \
                const int row = w * 32 + q * 16 + sr;                                \
                __builtin_amdgcn_global_load_lds(                                    \
                    (const __attribute__((address_space(1))) void*)                  \
                        (gA + (size_t)row * DI + (k0) + schunk * 8),                 \
                    (__attribute__((address_space(3))) void*)                        \
                        &As[bufi][(w * 32 + q * 16) * BK],                           \
                    16, 0, 0);                                                       \
                __builtin_amdgcn_global_load_lds(                                    \
                    (const __attribute__((address_space(1))) void*)                  \
                        (gB + (size_t)row * DI + (k0) + schunk * 8),                 \
                    (__attribute__((address_space(3))) void*)                        \
                        &Bs[bufi][(w * 32 + q * 16) * BK],                           \
                    16, 0, 0);                                                       \
            }                                                                        \
        } while (0)

    STAGE(0, 0);
    __syncthreads();

    int buf = 0;
    #pragma unroll 1
    for (int step = 0; step < DI / BK; ++step) {
        if (step + 1 < DI / BK)
            STAGE(buf ^ 1, (step + 1) * BK);

        bf16x8 af[4], bf[4];
        #pragma unroll
        for (int mi = 0; mi < 4; ++mi) {
            const int m = wr * 64 + mi * 16 + l15;
            af[mi] = *(const bf16x8*)&As[buf][m * BK + koff];
        }
        #pragma unroll
        for (int ni = 0; ni < 4; ++ni) {
            const int n = wc * 64 + ni * 16 + l15;
            bf[ni] = *(const bf16x8*)&Bs[buf][n * BK + koff];
        }

        #pragma unroll
        for (int mi = 0; mi < 4; ++mi)
            #pragma unroll
            for (int ni = 0; ni < 4; ++ni)
                acc[mi][ni] = __builtin_amdgcn_mfma_f32_16x16x32_bf16(
                                  af[mi], bf[ni], acc[mi][ni], 0, 0, 0);

        __syncthreads();   // buf consumed; staged buf^1 drained (vmcnt0)
        buf ^= 1;
    }
    #undef STAGE

    // epilogue: D col = l15 (n), row = kg*4 + r (m)
    float bs[4];
    #pragma unroll
    for (int ni = 0; ni < 4; ++ni)
        bs[ni] = bias[(size_t)cat * DO + nbase + wc * 64 + ni * 16 + l15];

    #pragma unroll
    for (int mi = 0; mi < 4; ++mi) {
        const int rowb = mbase + wr * 64 + mi * 16 + kg * 4;
        #pragma unroll
        for (int r = 0; r < 4; ++r) {
            float* orow = out + (size_t)(b * ST + rowb + r) * DO
                              + nbase + wc * 64 + l15;
            #pragma unroll
            for (int ni = 0; ni < 4; ++ni)
                orow[ni * 16] = acc[mi][ni][r] + bs[ni];
        }
    }
}

// ---------------- Fallback: correct fp32 path ----------------
__global__ __launch_bounds__(256) void naive_kernel(
        const float* __restrict__ x, const int* __restrict__ cat_ids,
        const float* __restrict__ W, const float* __restrict__ bias,
        float* __restrict__ out) {
    const int bt = blockIdx.x;
    const int b  = bt >> 9;
    const int t  = bt & 511;
    const int cat = cat_ids[b];
    const float* xr = x + ((size_t)b * ST + t) * DI;
    const float* Wc = W + (size_t)cat * DI * DO;
    const int o = threadIdx.x;
    float a0 = bias[cat * DO + o];
    float a1 = bias[cat * DO + o + 256];
    float a2 = bias[cat * DO + o + 512];
    float a3 = bias[cat * DO + o + 768];
    for (int i = 0; i < DI; ++i) {
        const float xv = xr[i];
        const float* wrow = Wc + (size_t)i * DO;
        a0 += xv * wrow[o];
        a1 += xv * wrow[o + 256];
        a2 += xv * wrow[o + 512];
        a3 += xv * wrow[o + 768];
    }
    float* orow = out + ((size_t)b * ST + t) * DO;
    orow[o] = a0; orow[o + 256] = a1; orow[o + 512] = a2; orow[o + 768] = a3;
}

extern "C" void kernel_launch(void* const* d_in, const int* in_sizes, int n_in,
                              void* d_out, int out_size, void* d_ws, size_t ws_size,
                              hipStream_t stream) {
    const float* x    = (const float*)d_in[0];
    const int*   cats = (const int*)d_in[1];
    const float* W    = (const float*)d_in[2];
    const float* bias = (const float*)d_in[3];
    float*       out  = (float*)d_out;

    const size_t wt_bytes = (size_t)CATS * DI * DO * sizeof(unsigned short); // 64 MiB
    const size_t xb_bytes = (size_t)NB * ST * DI * sizeof(unsigned short);   // 64 MiB

    if (ws_size >= wt_bytes + xb_bytes) {
        unsigned short* Wt = (unsigned short*)d_ws;
        unsigned short* xb = (unsigned short*)((char*)d_ws + wt_bytes);
        wt_transpose_kernel<<<dim3(DO / 64, DI / 128, CATS), 256, 0, stream>>>(W, Wt);
        x_convert_kernel<<<(NB * ST * DI) / (256 * 8), 256, 0, stream>>>(x, xb);
        cat_gemm_kernel<<<dim3(DO / BN, ST / BM, NB), 256, 0, stream>>>(
            xb, cats, Wt, bias, out);
    } else {
        naive_kernel<<<NB * ST, 256, 0, stream>>>(x, cats, W, bias, out);
    }
}